// Round 9
// baseline (101.475 us; speedup 1.0000x reference)
//
#include <hip/hip_runtime.h>
#include <hip/hip_fp16.h>

// NCC loss: two streaming passes + tiny reduce.
// K1 (ncc_hw): wave = (b,d,chunk); lanes = staggered w. Marches H (8 segs
//   x 20 + 8 halo) with a 5ch x 9 register ring (mod-9 static slots), then
//   the W 9-tap via a 4-shuffle tree per channel on output steps (TAP9 in
//   the PRODUCER, where rounds 6/7 proved it is absorbed), writing 5 PLANAR
//   fp16 streams of HW-window sums.
// K2 (ncc_d): the round-2-proven golden consumer: thread per (b,h,w)
//   marches D over the 5 planar fp16 streams with a 5ch x 9 ring + fp32
//   ncc + block reduce. No shuffles, no LDS in the loop.
// K3: deterministic final reduction.

constexpr int BB = 2, DD = 160, HH = 160, WW = 160;
constexpr int SLICE = HH * WW;                         // 25600
constexpr long long NTOT = (long long)BB * DD * SLICE; // 8,192,000
constexpr int HSEG = 20, NHSEG = 8;                    // K1 h-segments
constexpr int DSEG = 20, NDSEG = 8;                    // K2 d-segments
constexpr int NPART = 200 * NDSEG;                     // 1600 partials

// 9-tap in-wave box sum: v[l] <- sum_{k=0..8} v[l+k]  (valid for l <= 55)
#define TAP9(v)                                                        \
  {                                                                    \
    float _t1 = __shfl_down(v, 1, 64), _t2 = __shfl_down(v, 2, 64);    \
    v = v + _t1 + _t2;                                                 \
    float _t3 = __shfl_down(v, 3, 64), _t6 = __shfl_down(v, 6, 64);    \
    v = v + _t3 + _t6;                                                 \
  }

// ---------- K1: H-ring + in-wave W-sum, planar fp16 out ----------
__global__ __launch_bounds__(256) void ncc_hw_kernel(
    const float* __restrict__ f, const float* __restrict__ w,
    __half* __restrict__ p0, __half* __restrict__ p1, __half* __restrict__ p2,
    __half* __restrict__ p3, __half* __restrict__ p4) {
  const int tid = threadIdx.x;
  const int lane = tid & 63;
  const int wid = (blockIdx.x << 2) | (tid >> 6);  // 0..959 : (b,d,chunk)
  const int b = wid / 480;
  const int rem = wid % 480;
  const int d = rem / 3;
  const int ck = rem % 3;
  const int w_in = ck * 56 - 4 + lane;             // staggered input lane
  const int w_out = ck * 56 + lane;
  const bool vin = (unsigned)w_in < 160u;
  const bool vout = (lane < 56) && (w_out < 160);
  const int h0 = blockIdx.y * HSEG;
  const long long sb = (long long)(b * DD + d) * SLICE;
  const float* fr = f + sb + w_in;
  const float* wr = w + sb + w_in;

  float r0[9], r1[9], r2[9], r3[9], r4[9];
#pragma unroll
  for (int k = 0; k < 9; ++k) { r0[k] = r1[k] = r2[k] = r3[k] = r4[k] = 0.f; }
  float S0 = 0.f, S1 = 0.f, S2 = 0.f, S3 = 0.f, S4 = 0.f;

#pragma unroll
  for (int p = 0; p < HSEG + 8; ++p) {             // 28 steps
    const int j = h0 - 4 + p;                      // block-uniform guard
    float vf = 0.f, vw = 0.f;
    if ((unsigned)j < 160u && vin) {
      vf = fr[(long long)j * WW];
      vw = wr[(long long)j * WW];
    }
    const float a2 = vf * vf, a3 = vw * vw, a4 = vf * vw;
    const int sl = p % 9;                          // static after unroll
    S0 += vf - r0[sl]; r0[sl] = vf;
    S1 += vw - r1[sl]; r1[sl] = vw;
    S2 += a2 - r2[sl]; r2[sl] = a2;
    S3 += a3 - r3[sl]; r3[sl] = a3;
    S4 += a4 - r4[sl]; r4[sl] = a4;

    if (p >= 8) {
      float z0 = S0, z1 = S1, z2 = S2, z3 = S3, z4 = S4;
      TAP9(z0); TAP9(z1); TAP9(z2); TAP9(z3); TAP9(z4);
      if (vout) {
        const long long a = sb + (long long)(h0 + p - 8) * WW + w_out;
        p0[a] = __float2half_rn(z0);
        p1[a] = __float2half_rn(z1);
        p2[a] = __float2half_rn(z2);
        p3[a] = __float2half_rn(z3);
        p4[a] = __float2half_rn(z4);
      }
    }
  }
}

// ---------- K2: D-ring + ncc (golden round-2 consumer shape) ----------
__global__ __launch_bounds__(256) void ncc_d_kernel(
    const __half* __restrict__ p0, const __half* __restrict__ p1,
    const __half* __restrict__ p2, const __half* __restrict__ p3,
    const __half* __restrict__ p4, float* __restrict__ partials) {
  const int tid = threadIdx.x;
  const int g = blockIdx.x * 256 + tid;            // 0..51199 : (b, hw)
  const int b = g / SLICE;                         // blocks don't straddle b
  const int r = g % SLICE;
  const int d0 = blockIdx.y * DSEG;
  const long long base = (long long)b * DD * SLICE + r;

  float r0[9], r1[9], r2[9], r3[9], r4[9];
#pragma unroll
  for (int k = 0; k < 9; ++k) { r0[k] = r1[k] = r2[k] = r3[k] = r4[k] = 0.f; }
  float S0 = 0.f, S1 = 0.f, S2 = 0.f, S3 = 0.f, S4 = 0.f, acc = 0.f;
  const float inv = 1.0f / 729.0f;

#pragma unroll
  for (int p = 0; p < DSEG + 8; ++p) {             // 28 steps
    const int j = d0 - 4 + p;                      // block-uniform guard
    float n0 = 0.f, n1 = 0.f, n2 = 0.f, n3 = 0.f, n4 = 0.f;
    if ((unsigned)j < 160u) {
      const long long a = base + (long long)j * SLICE;
      n0 = __half2float(p0[a]);
      n1 = __half2float(p1[a]);
      n2 = __half2float(p2[a]);
      n3 = __half2float(p3[a]);
      n4 = __half2float(p4[a]);
    }
    const int sl = p % 9;                          // static after unroll
    S0 += n0 - r0[sl]; r0[sl] = n0;
    S1 += n1 - r1[sl]; r1[sl] = n1;
    S2 += n2 - r2[sl]; r2[sl] = n2;
    S3 += n3 - r3[sl]; r3[sl] = n3;
    S4 += n4 - r4[sl]; r4[sl] = n4;

    if (p >= 8) {
      const float fm = S0 * inv, wm = S1 * inv;
      const float fv = S2 * inv - fm * fm;
      const float wv = S3 * inv - wm * wm;
      const float cov = S4 * inv - fm * wm;
      const float den = sqrtf(fmaxf(fv, 0.f) + 1e-8f) *
                        sqrtf(fmaxf(wv, 0.f) + 1e-8f);
      acc += fminf(1.f, fmaxf(-1.f, cov / den));
    }
  }

  __shared__ float red[256];
  red[tid] = acc;
  __syncthreads();
#pragma unroll
  for (int st = 128; st > 0; st >>= 1) {
    if (tid < st) red[tid] += red[tid + st];
    __syncthreads();
  }
  if (tid == 0) partials[blockIdx.y * gridDim.x + blockIdx.x] = red[0];
}

// ---------------- K3: final reduction ----------------
__global__ __launch_bounds__(1024) void ncc_final_kernel(
    const float* __restrict__ partials, float* __restrict__ out) {
  const int t = threadIdx.x;
  float a = 0.f;
  for (int i = t; i < NPART; i += 1024) a += partials[i];
#pragma unroll
  for (int off = 32; off > 0; off >>= 1) a += __shfl_down(a, off, 64);
  __shared__ float wr[16];
  if ((t & 63) == 0) wr[t >> 6] = a;
  __syncthreads();
  if (t == 0) {
    float s = 0.f;
#pragma unroll
    for (int k = 0; k < 16; ++k) s += wr[k];
    out[0] = -s * (1.0f / (float)NTOT);
  }
}

extern "C" void kernel_launch(void* const* d_in, const int* in_sizes, int n_in,
                              void* d_out, int out_size, void* d_ws, size_t ws_size,
                              hipStream_t stream) {
  const float* fixed = (const float*)d_in[0];
  const float* warped = (const float*)d_in[1];
  float* out = (float*)d_out;

  __half* p0 = (__half*)d_ws;                        // 5 planes x 16.4 MB
  __half* p1 = p0 + NTOT;
  __half* p2 = p1 + NTOT;
  __half* p3 = p2 + NTOT;
  __half* p4 = p3 + NTOT;
  float* partials = (float*)((char*)d_ws + (size_t)NTOT * 10);  // 6.4 KB

  dim3 g1(240, NHSEG);            // 960 waves x 8 h-segs = 1920 blocks
  ncc_hw_kernel<<<g1, dim3(256), 0, stream>>>(fixed, warped, p0, p1, p2, p3, p4);

  dim3 g2(200, NDSEG);            // 1600 blocks x 256
  ncc_d_kernel<<<g2, dim3(256), 0, stream>>>(p0, p1, p2, p3, p4, partials);

  ncc_final_kernel<<<1, dim3(1024), 0, stream>>>(partials, out);
}

// Round 10
// 79.203 us; speedup vs baseline: 1.2812x; 1.2812x over previous
//
#include <hip/hip_runtime.h>
#include <hip/hip_fp16.h>

// NCC loss: two streaming passes + tiny reduce.
// K1 (ncc_h): thread per (b,d,w) marches H (8 segs x 20 + 8 halo) with a
//   5ch x 9 register ring (mod-9 static slots). Reads raw f,w coalesced;
//   writes 3 PLANAR uint streams of fp16-PAIRED H-window sums:
//   q01 = (S0,S1), q23 = (S2,S3), q4 = (S4,0). All-dword consumer loads.
// K2 (ncc_dw): wave = (b,h,chunk); lanes = staggered w. Marches D with a
//   5ch x 9 f32 ring fed by 3 dword loads/step (was 5 ushort - the r1/r9
//   cross-round evidence says sub-dword planar loads are the consumer's
//   ~45us floor), then the W 9-tap on PACKED __half2 (12 shuffles + 12
//   v_pk_add_f16, was 20+20), then fp32 ncc + block reduce.
// K3: deterministic final reduction.

constexpr int BB = 2, DD = 160, HH = 160, WW = 160;
constexpr int SLICE = HH * WW;                         // 25600
constexpr long long NTOT = (long long)BB * DD * SLICE; // 8,192,000
constexpr int HSEG = 20, NHSEG = 8;                    // K1 h-segments
constexpr int DSEG = 20, NDSEG = 8;                    // K2 d-segments
constexpr int NPART = 240 * NDSEG;                     // 1920 partials

static __device__ __forceinline__ unsigned pkh(float a, float b) {
  __half2 h = __floats2half2_rn(a, b);
  return __builtin_bit_cast(unsigned, h);
}

// 9-tap in-wave box sum on packed __half2 (both halves independently):
// v[l] <- sum_{k=0..8} v[l+k]   (valid for lane <= 55)
#define TAP9H(v)                                                         \
  {                                                                      \
    unsigned _u = __builtin_bit_cast(unsigned, v);                       \
    __half2 _t1 = __builtin_bit_cast(__half2, __shfl_down(_u, 1, 64));   \
    __half2 _t2 = __builtin_bit_cast(__half2, __shfl_down(_u, 2, 64));   \
    v = v + _t1 + _t2;                                                   \
    _u = __builtin_bit_cast(unsigned, v);                                \
    __half2 _t3 = __builtin_bit_cast(__half2, __shfl_down(_u, 3, 64));   \
    __half2 _t6 = __builtin_bit_cast(__half2, __shfl_down(_u, 6, 64));   \
    v = v + _t3 + _t6;                                                   \
  }

// ---------------- K1: H-axis window sums, 3 packed planar streams ----------------
__global__ __launch_bounds__(256) void ncc_h_kernel(
    const float* __restrict__ f, const float* __restrict__ w,
    unsigned* __restrict__ q01, unsigned* __restrict__ q23,
    unsigned* __restrict__ q4) {
  const int tid = threadIdx.x;
  const int g = blockIdx.x * 256 + tid;      // 0..51199 : (b,d,w)
  const int wq = g % 160;
  const int t2 = g / 160;
  const int d = t2 % 160;
  const int b = t2 / 160;
  const int h0 = blockIdx.y * HSEG;
  const long long base = (long long)(b * DD + d) * SLICE + wq;   // + j*WW

  float r0[9], r1[9], r2[9], r3[9], r4[9];
#pragma unroll
  for (int k = 0; k < 9; ++k) { r0[k] = r1[k] = r2[k] = r3[k] = r4[k] = 0.f; }
  float S0 = 0.f, S1 = 0.f, S2 = 0.f, S3 = 0.f, S4 = 0.f;

#pragma unroll
  for (int p = 0; p < HSEG + 8; ++p) {       // 28 steps
    const int j = h0 - 4 + p;                // block-uniform guard
    float vf = 0.f, vw = 0.f;
    if ((unsigned)j < 160u) {
      const long long a = base + (long long)j * WW;
      vf = f[a];
      vw = w[a];
    }
    const float a2 = vf * vf, a3 = vw * vw, a4 = vf * vw;
    const int sl = p % 9;                    // static after unroll
    S0 += vf - r0[sl]; r0[sl] = vf;
    S1 += vw - r1[sl]; r1[sl] = vw;
    S2 += a2 - r2[sl]; r2[sl] = a2;
    S3 += a3 - r3[sl]; r3[sl] = a3;
    S4 += a4 - r4[sl]; r4[sl] = a4;
    if (p >= 8) {
      const long long a = base + (long long)(h0 + p - 8) * WW;
      q01[a] = pkh(S0, S1);
      q23[a] = pkh(S2, S3);
      q4[a]  = pkh(S4, 0.f);
    }
  }
}

// ---------------- K2: D-ring (dword loads) + packed-TAP9 W-sum + ncc ----------------
__global__ __launch_bounds__(256) void ncc_dw_kernel(
    const unsigned* __restrict__ q01, const unsigned* __restrict__ q23,
    const unsigned* __restrict__ q4, float* __restrict__ partials) {
  const int tid = threadIdx.x;
  const int lane = tid & 63;
  const int wid = (blockIdx.x << 2) | (tid >> 6);  // 0..959 : (b,h,chunk)
  const int b = wid / 480;
  const int rem = wid % 480;
  const int h = rem / 3;
  const int ck = rem % 3;
  const int w_in = ck * 56 - 4 + lane;             // staggered input lane
  const int w_out = ck * 56 + lane;
  const bool vin = (unsigned)w_in < 160u;
  const bool vout = (lane < 56) && (w_out < 160);
  const int d0 = blockIdx.y * DSEG;
  const long long cb = (long long)b * DD * SLICE + (long long)h * WW + w_in;

  float r0[9], r1[9], r2[9], r3[9], r4[9];
#pragma unroll
  for (int k = 0; k < 9; ++k) { r0[k] = r1[k] = r2[k] = r3[k] = r4[k] = 0.f; }
  float S0 = 0.f, S1 = 0.f, S2 = 0.f, S3 = 0.f, S4 = 0.f, acc = 0.f;
  const float inv = 1.0f / 729.0f;

#pragma unroll
  for (int p = 0; p < DSEG + 8; ++p) {             // 28 steps
    const int j = d0 - 4 + p;                      // uniform guard
    float n0 = 0.f, n1 = 0.f, n2 = 0.f, n3 = 0.f, n4 = 0.f;
    if ((unsigned)j < 160u && vin) {
      const long long a = cb + (long long)j * SLICE;
      const float2 p01 = __half22float2(__builtin_bit_cast(__half2, q01[a]));
      const float2 p23 = __half22float2(__builtin_bit_cast(__half2, q23[a]));
      const float2 p4v = __half22float2(__builtin_bit_cast(__half2, q4[a]));
      n0 = p01.x; n1 = p01.y; n2 = p23.x; n3 = p23.y; n4 = p4v.x;
    }
    const int sl = p % 9;                          // static after unroll
    S0 += n0 - r0[sl]; r0[sl] = n0;
    S1 += n1 - r1[sl]; r1[sl] = n1;
    S2 += n2 - r2[sl]; r2[sl] = n2;
    S3 += n3 - r3[sl]; r3[sl] = n3;
    S4 += n4 - r4[sl]; r4[sl] = n4;

    if (p >= 8) {
      // pack the five D-window sums into 3 half2 regs, TAP9 on packed lanes
      __half2 z01 = __floats2half2_rn(S0, S1);
      __half2 z23 = __floats2half2_rn(S2, S3);
      __half2 z4x = __floats2half2_rn(S4, 0.f);
      TAP9H(z01); TAP9H(z23); TAP9H(z4x);
      if (vout) {
        const float2 a01 = __half22float2(z01);
        const float2 a23 = __half22float2(z23);
        const float2 a4v = __half22float2(z4x);
        const float fm = a01.x * inv, wm = a01.y * inv;
        const float fv = a23.x * inv - fm * fm;
        const float wv = a23.y * inv - wm * wm;
        const float cov = a4v.x * inv - fm * wm;
        const float den = sqrtf(fmaxf(fv, 0.f) + 1e-8f) *
                          sqrtf(fmaxf(wv, 0.f) + 1e-8f);
        acc += fminf(1.f, fmaxf(-1.f, cov / den));
      }
    }
  }

  __shared__ float red[256];
  red[tid] = acc;
  __syncthreads();
#pragma unroll
  for (int st = 128; st > 0; st >>= 1) {
    if (tid < st) red[tid] += red[tid + st];
    __syncthreads();
  }
  if (tid == 0) partials[blockIdx.y * gridDim.x + blockIdx.x] = red[0];
}

// ---------------- K3: final reduction ----------------
__global__ __launch_bounds__(1024) void ncc_final_kernel(
    const float* __restrict__ partials, float* __restrict__ out) {
  const int t = threadIdx.x;
  float a = 0.f;
  for (int i = t; i < NPART; i += 1024) a += partials[i];
#pragma unroll
  for (int off = 32; off > 0; off >>= 1) a += __shfl_down(a, off, 64);
  __shared__ float wr[16];
  if ((t & 63) == 0) wr[t >> 6] = a;
  __syncthreads();
  if (t == 0) {
    float s = 0.f;
#pragma unroll
    for (int k = 0; k < 16; ++k) s += wr[k];
    out[0] = -s * (1.0f / (float)NTOT);
  }
}

extern "C" void kernel_launch(void* const* d_in, const int* in_sizes, int n_in,
                              void* d_out, int out_size, void* d_ws, size_t ws_size,
                              hipStream_t stream) {
  const float* fixed = (const float*)d_in[0];
  const float* warped = (const float*)d_in[1];
  float* out = (float*)d_out;

  unsigned* q01 = (unsigned*)d_ws;                               // 32.77 MB
  unsigned* q23 = q01 + NTOT;                                    // 32.77 MB
  unsigned* q4  = q23 + NTOT;                                    // 32.77 MB
  float* partials = (float*)((char*)d_ws + (size_t)NTOT * 12);   // 7.7 KB

  dim3 g1(200, NHSEG);            // 1600 blocks x 256
  ncc_h_kernel<<<g1, dim3(256), 0, stream>>>(fixed, warped, q01, q23, q4);

  dim3 g2(240, NDSEG);            // 960 waves x 8 d-segs = 1920 blocks
  ncc_dw_kernel<<<g2, dim3(256), 0, stream>>>(q01, q23, q4, partials);

  ncc_final_kernel<<<1, dim3(1024), 0, stream>>>(partials, out);
}

// Round 11
// 73.642 us; speedup vs baseline: 1.3779x; 1.0755x over previous
//
#include <hip/hip_runtime.h>
#include <hip/hip_fp16.h>

// NCC loss: two streaming passes + tiny reduce.
// K1 (ncc_h): thread per (b,d,w) marches H (8 segs x 20 + 8 halo) with a
//   5ch x 9 register ring (mod-9 static slots). Reads raw f,w coalesced;
//   writes 3 PLANAR uint streams of fp16-PAIRED H-window sums.
// K2 (ncc_dw): wave = (b,h,chunk); lanes = staggered w. Marches D with a
//   5ch x 9 f32 ring fed by 3 dword loads/step, then the W 9-tap on PACKED
//   __half2 (12 shuffles + 12 pk_add), then fp32 ncc + block reduce.
//   ROUND-11 FIX: __launch_bounds__(256,4) so the register allocator keeps
//   the 45-value ring LIVE (r10's VGPR=36 proved it was rematerializing /
//   spilling it -> the ~50us consumer floor), and 1-rsqrt ncc tail.
// K3: deterministic final reduction.

constexpr int BB = 2, DD = 160, HH = 160, WW = 160;
constexpr int SLICE = HH * WW;                         // 25600
constexpr long long NTOT = (long long)BB * DD * SLICE; // 8,192,000
constexpr int HSEG = 20, NHSEG = 8;                    // K1 h-segments
constexpr int DSEG = 20, NDSEG = 8;                    // K2 d-segments
constexpr int NPART = 240 * NDSEG;                     // 1920 partials

static __device__ __forceinline__ unsigned pkh(float a, float b) {
  __half2 h = __floats2half2_rn(a, b);
  return __builtin_bit_cast(unsigned, h);
}

// 9-tap in-wave box sum on packed __half2 (both halves independently):
// v[l] <- sum_{k=0..8} v[l+k]   (valid for lane <= 55)
#define TAP9H(v)                                                         \
  {                                                                      \
    unsigned _u = __builtin_bit_cast(unsigned, v);                       \
    __half2 _t1 = __builtin_bit_cast(__half2, __shfl_down(_u, 1, 64));   \
    __half2 _t2 = __builtin_bit_cast(__half2, __shfl_down(_u, 2, 64));   \
    v = v + _t1 + _t2;                                                   \
    _u = __builtin_bit_cast(unsigned, v);                                \
    __half2 _t3 = __builtin_bit_cast(__half2, __shfl_down(_u, 3, 64));   \
    __half2 _t6 = __builtin_bit_cast(__half2, __shfl_down(_u, 6, 64));   \
    v = v + _t3 + _t6;                                                   \
  }

// ---------------- K1: H-axis window sums, 3 packed planar streams ----------------
__global__ __launch_bounds__(256, 4) void ncc_h_kernel(
    const float* __restrict__ f, const float* __restrict__ w,
    unsigned* __restrict__ q01, unsigned* __restrict__ q23,
    unsigned* __restrict__ q4) {
  const int tid = threadIdx.x;
  const int g = blockIdx.x * 256 + tid;      // 0..51199 : (b,d,w)
  const int wq = g % 160;
  const int t2 = g / 160;
  const int d = t2 % 160;
  const int b = t2 / 160;
  const int h0 = blockIdx.y * HSEG;
  const long long base = (long long)(b * DD + d) * SLICE + wq;   // + j*WW

  float r0[9], r1[9], r2[9], r3[9], r4[9];
#pragma unroll
  for (int k = 0; k < 9; ++k) { r0[k] = r1[k] = r2[k] = r3[k] = r4[k] = 0.f; }
  float S0 = 0.f, S1 = 0.f, S2 = 0.f, S3 = 0.f, S4 = 0.f;

#pragma unroll
  for (int p = 0; p < HSEG + 8; ++p) {       // 28 steps
    const int j = h0 - 4 + p;                // block-uniform guard
    float vf = 0.f, vw = 0.f;
    if ((unsigned)j < 160u) {
      const long long a = base + (long long)j * WW;
      vf = f[a];
      vw = w[a];
    }
    const float a2 = vf * vf, a3 = vw * vw, a4 = vf * vw;
    const int sl = p % 9;                    // static after unroll
    S0 += vf - r0[sl]; r0[sl] = vf;
    S1 += vw - r1[sl]; r1[sl] = vw;
    S2 += a2 - r2[sl]; r2[sl] = a2;
    S3 += a3 - r3[sl]; r3[sl] = a3;
    S4 += a4 - r4[sl]; r4[sl] = a4;
    if (p >= 8) {
      const long long a = base + (long long)(h0 + p - 8) * WW;
      q01[a] = pkh(S0, S1);
      q23[a] = pkh(S2, S3);
      q4[a]  = pkh(S4, 0.f);
    }
  }
}

// ---------------- K2: D-ring (dword loads) + packed-TAP9 W-sum + ncc ----------------
__global__ __launch_bounds__(256, 4) void ncc_dw_kernel(
    const unsigned* __restrict__ q01, const unsigned* __restrict__ q23,
    const unsigned* __restrict__ q4, float* __restrict__ partials) {
  const int tid = threadIdx.x;
  const int lane = tid & 63;
  const int wid = (blockIdx.x << 2) | (tid >> 6);  // 0..959 : (b,h,chunk)
  const int b = wid / 480;
  const int rem = wid % 480;
  const int h = rem / 3;
  const int ck = rem % 3;
  const int w_in = ck * 56 - 4 + lane;             // staggered input lane
  const int w_out = ck * 56 + lane;
  const bool vin = (unsigned)w_in < 160u;
  const bool vout = (lane < 56) && (w_out < 160);
  const int d0 = blockIdx.y * DSEG;
  const long long cb = (long long)b * DD * SLICE + (long long)h * WW + w_in;

  float r0[9], r1[9], r2[9], r3[9], r4[9];
#pragma unroll
  for (int k = 0; k < 9; ++k) { r0[k] = r1[k] = r2[k] = r3[k] = r4[k] = 0.f; }
  float S0 = 0.f, S1 = 0.f, S2 = 0.f, S3 = 0.f, S4 = 0.f, acc = 0.f;
  const float inv = 1.0f / 729.0f;

#pragma unroll
  for (int p = 0; p < DSEG + 8; ++p) {             // 28 steps
    const int j = d0 - 4 + p;                      // uniform guard
    float n0 = 0.f, n1 = 0.f, n2 = 0.f, n3 = 0.f, n4 = 0.f;
    if ((unsigned)j < 160u && vin) {
      const long long a = cb + (long long)j * SLICE;
      const float2 p01 = __half22float2(__builtin_bit_cast(__half2, q01[a]));
      const float2 p23 = __half22float2(__builtin_bit_cast(__half2, q23[a]));
      const float2 p4v = __half22float2(__builtin_bit_cast(__half2, q4[a]));
      n0 = p01.x; n1 = p01.y; n2 = p23.x; n3 = p23.y; n4 = p4v.x;
    }
    const int sl = p % 9;                          // static after unroll
    S0 += n0 - r0[sl]; r0[sl] = n0;
    S1 += n1 - r1[sl]; r1[sl] = n1;
    S2 += n2 - r2[sl]; r2[sl] = n2;
    S3 += n3 - r3[sl]; r3[sl] = n3;
    S4 += n4 - r4[sl]; r4[sl] = n4;

    if (p >= 8) {
      // pack the five D-window sums into 3 half2 regs, TAP9 on packed lanes
      __half2 z01 = __floats2half2_rn(S0, S1);
      __half2 z23 = __floats2half2_rn(S2, S3);
      __half2 z4x = __floats2half2_rn(S4, 0.f);
      TAP9H(z01); TAP9H(z23); TAP9H(z4x);
      if (vout) {
        const float2 a01 = __half22float2(z01);
        const float2 a23 = __half22float2(z23);
        const float2 a4v = __half22float2(z4x);
        const float fm = a01.x * inv, wm = a01.y * inv;
        const float fv = a23.x * inv - fm * fm;
        const float wv = a23.y * inv - wm * wm;
        const float cov = a4v.x * inv - fm * wm;
        const float den2 = (fmaxf(fv, 0.f) + 1e-8f) * (fmaxf(wv, 0.f) + 1e-8f);
        const float ncc = cov * rsqrtf(den2);      // == cov/(sqrt*sqrt)
        acc += fminf(1.f, fmaxf(-1.f, ncc));
      }
    }
  }

  __shared__ float red[256];
  red[tid] = acc;
  __syncthreads();
#pragma unroll
  for (int st = 128; st > 0; st >>= 1) {
    if (tid < st) red[tid] += red[tid + st];
    __syncthreads();
  }
  if (tid == 0) partials[blockIdx.y * gridDim.x + blockIdx.x] = red[0];
}

// ---------------- K3: final reduction ----------------
__global__ __launch_bounds__(1024) void ncc_final_kernel(
    const float* __restrict__ partials, float* __restrict__ out) {
  const int t = threadIdx.x;
  float a = 0.f;
  for (int i = t; i < NPART; i += 1024) a += partials[i];
#pragma unroll
  for (int off = 32; off > 0; off >>= 1) a += __shfl_down(a, off, 64);
  __shared__ float wr[16];
  if ((t & 63) == 0) wr[t >> 6] = a;
  __syncthreads();
  if (t == 0) {
    float s = 0.f;
#pragma unroll
    for (int k = 0; k < 16; ++k) s += wr[k];
    out[0] = -s * (1.0f / (float)NTOT);
  }
}

extern "C" void kernel_launch(void* const* d_in, const int* in_sizes, int n_in,
                              void* d_out, int out_size, void* d_ws, size_t ws_size,
                              hipStream_t stream) {
  const float* fixed = (const float*)d_in[0];
  const float* warped = (const float*)d_in[1];
  float* out = (float*)d_out;

  unsigned* q01 = (unsigned*)d_ws;                               // 32.77 MB
  unsigned* q23 = q01 + NTOT;                                    // 32.77 MB
  unsigned* q4  = q23 + NTOT;                                    // 32.77 MB
  float* partials = (float*)((char*)d_ws + (size_t)NTOT * 12);   // 7.7 KB

  dim3 g1(200, NHSEG);            // 1600 blocks x 256
  ncc_h_kernel<<<g1, dim3(256), 0, stream>>>(fixed, warped, q01, q23, q4);

  dim3 g2(240, NDSEG);            // 960 waves x 8 d-segs = 1920 blocks
  ncc_dw_kernel<<<g2, dim3(256), 0, stream>>>(q01, q23, q4, partials);

  ncc_final_kernel<<<1, dim3(1024), 0, stream>>>(partials, out);
}

// Round 12
// 66.312 us; speedup vs baseline: 1.5303x; 1.1105x over previous
//
#include <hip/hip_runtime.h>
#include <hip/hip_fp16.h>

// NCC loss: two streaming passes + tiny reduce.
// K1 (ncc_h): thread per (b,d,w) marches H (8 segs x 20 + 8 halo) with a
//   5ch x 9 f32 register ring (mod-9 static slots). Reads raw f,w coalesced;
//   writes INTERLEAVED 12B records {q01,q23,q4} (fp16 pairs) per voxel ->
//   consumer gets ONE merged dwordx3 load stream.
// K2 (ncc_dw): wave = (b,h,chunk); lanes = staggered w. Marches D keeping
//   the 9-slice ring PACKED (27 uint regs, was 45 f32 - round-10/11 showed
//   the compiler refuses to hold the f32 ring + loads in regs, VGPR=36).
//   D-window = tree-sum of all 9 packed slots (8 pk_add x 3 streams, fresh
//   each output -> bounded fp16 err), then W 9-tap TAP9H, then fp32 ncc.
// K3: deterministic final reduction.

constexpr int BB = 2, DD = 160, HH = 160, WW = 160;
constexpr int SLICE = HH * WW;                         // 25600
constexpr long long NTOT = (long long)BB * DD * SLICE; // 8,192,000
constexpr int HSEG = 20, NHSEG = 8;                    // K1 h-segments
constexpr int DSEG = 20, NDSEG = 8;                    // K2 d-segments
constexpr int NPART = 240 * NDSEG;                     // 1920 partials

static __device__ __forceinline__ unsigned pkh(float a, float b) {
  __half2 h = __floats2half2_rn(a, b);
  return __builtin_bit_cast(unsigned, h);
}
static __device__ __forceinline__ __half2 h2(unsigned u) {
  return __builtin_bit_cast(__half2, u);
}

// 9-tap in-wave box sum on packed __half2 (both halves independently):
// v[l] <- sum_{k=0..8} v[l+k]   (valid for lane <= 55)
#define TAP9H(v)                                                         \
  {                                                                      \
    unsigned _u = __builtin_bit_cast(unsigned, v);                       \
    __half2 _t1 = __builtin_bit_cast(__half2, __shfl_down(_u, 1, 64));   \
    __half2 _t2 = __builtin_bit_cast(__half2, __shfl_down(_u, 2, 64));   \
    v = v + _t1 + _t2;                                                   \
    _u = __builtin_bit_cast(unsigned, v);                                \
    __half2 _t3 = __builtin_bit_cast(__half2, __shfl_down(_u, 3, 64));   \
    __half2 _t6 = __builtin_bit_cast(__half2, __shfl_down(_u, 6, 64));   \
    v = v + _t3 + _t6;                                                   \
  }

// ---------------- K1: H-axis window sums, interleaved 12B records ----------------
__global__ __launch_bounds__(256, 4) void ncc_h_kernel(
    const float* __restrict__ f, const float* __restrict__ w,
    unsigned* __restrict__ q) {
  const int tid = threadIdx.x;
  const int g = blockIdx.x * 256 + tid;      // 0..51199 : (b,d,w)
  const int wq = g % 160;
  const int t2 = g / 160;
  const int d = t2 % 160;
  const int b = t2 / 160;
  const int h0 = blockIdx.y * HSEG;
  const long long base = (long long)(b * DD + d) * SLICE + wq;   // + j*WW

  float r0[9], r1[9], r2[9], r3[9], r4[9];
#pragma unroll
  for (int k = 0; k < 9; ++k) { r0[k] = r1[k] = r2[k] = r3[k] = r4[k] = 0.f; }
  float S0 = 0.f, S1 = 0.f, S2 = 0.f, S3 = 0.f, S4 = 0.f;

#pragma unroll
  for (int p = 0; p < HSEG + 8; ++p) {       // 28 steps
    const int j = h0 - 4 + p;                // block-uniform guard
    float vf = 0.f, vw = 0.f;
    if ((unsigned)j < 160u) {
      const long long a = base + (long long)j * WW;
      vf = f[a];
      vw = w[a];
    }
    const float a2 = vf * vf, a3 = vw * vw, a4 = vf * vw;
    const int sl = p % 9;                    // static after unroll
    S0 += vf - r0[sl]; r0[sl] = vf;
    S1 += vw - r1[sl]; r1[sl] = vw;
    S2 += a2 - r2[sl]; r2[sl] = a2;
    S3 += a3 - r3[sl]; r3[sl] = a3;
    S4 += a4 - r4[sl]; r4[sl] = a4;
    if (p >= 8) {
      const long long a = base + (long long)(h0 + p - 8) * WW;
      const long long i3 = a * 3;
      q[i3 + 0] = pkh(S0, S1);
      q[i3 + 1] = pkh(S2, S3);
      q[i3 + 2] = pkh(S4, 0.f);
    }
  }
}

// ---------------- K2: packed D-ring + tree-sum + TAP9H + ncc ----------------
__global__ __launch_bounds__(256, 4) void ncc_dw_kernel(
    const unsigned* __restrict__ q, float* __restrict__ partials) {
  const int tid = threadIdx.x;
  const int lane = tid & 63;
  const int wid = (blockIdx.x << 2) | (tid >> 6);  // 0..959 : (b,h,chunk)
  const int b = wid / 480;
  const int rem = wid % 480;
  const int h = rem / 3;
  const int ck = rem % 3;
  const int w_in = ck * 56 - 4 + lane;             // staggered input lane
  const int w_out = ck * 56 + lane;
  const bool vin = (unsigned)w_in < 160u;
  const bool vout = (lane < 56) && (w_out < 160);
  const int d0 = blockIdx.y * DSEG;
  const long long cb = (long long)b * DD * SLICE + (long long)h * WW + w_in;

  // packed 9-slice ring: 27 uint regs, static slots after full unroll
  unsigned g0[9], g1[9], g2[9];
#pragma unroll
  for (int k = 0; k < 9; ++k) { g0[k] = 0u; g1[k] = 0u; g2[k] = 0u; }
  float acc = 0.f;
  const float inv = 1.0f / 729.0f;

#pragma unroll
  for (int p = 0; p < DSEG + 8; ++p) {             // 28 steps
    const int j = d0 - 4 + p;                      // uniform guard
    unsigned u0 = 0u, u1 = 0u, u2 = 0u;
    if ((unsigned)j < 160u && vin) {
      const long long i3 = (cb + (long long)j * SLICE) * 3;
      u0 = q[i3 + 0];                              // merges to dwordx3
      u1 = q[i3 + 1];
      u2 = q[i3 + 2];
    }
    const int sl = p % 9;                          // static after unroll
    g0[sl] = u0; g1[sl] = u1; g2[sl] = u2;

    if (p >= 8) {
      // D-window = sum of ALL 9 ring slots (order-free), packed fp16 tree
      __half2 z01 = ((h2(g0[0]) + h2(g0[1])) + (h2(g0[2]) + h2(g0[3]))) +
                    ((h2(g0[4]) + h2(g0[5])) + (h2(g0[6]) + h2(g0[7]))) +
                    h2(g0[8]);
      __half2 z23 = ((h2(g1[0]) + h2(g1[1])) + (h2(g1[2]) + h2(g1[3]))) +
                    ((h2(g1[4]) + h2(g1[5])) + (h2(g1[6]) + h2(g1[7]))) +
                    h2(g1[8]);
      __half2 z4x = ((h2(g2[0]) + h2(g2[1])) + (h2(g2[2]) + h2(g2[3]))) +
                    ((h2(g2[4]) + h2(g2[5])) + (h2(g2[6]) + h2(g2[7]))) +
                    h2(g2[8]);
      TAP9H(z01); TAP9H(z23); TAP9H(z4x);
      if (vout) {
        const float2 a01 = __half22float2(z01);
        const float2 a23 = __half22float2(z23);
        const float2 a4v = __half22float2(z4x);
        const float fm = a01.x * inv, wm = a01.y * inv;
        const float fv = a23.x * inv - fm * fm;
        const float wv = a23.y * inv - wm * wm;
        const float cov = a4v.x * inv - fm * wm;
        const float den2 = (fmaxf(fv, 0.f) + 1e-8f) * (fmaxf(wv, 0.f) + 1e-8f);
        const float ncc = cov * rsqrtf(den2);
        acc += fminf(1.f, fmaxf(-1.f, ncc));
      }
    }
  }

  __shared__ float red[256];
  red[tid] = acc;
  __syncthreads();
#pragma unroll
  for (int st = 128; st > 0; st >>= 1) {
    if (tid < st) red[tid] += red[tid + st];
    __syncthreads();
  }
  if (tid == 0) partials[blockIdx.y * gridDim.x + blockIdx.x] = red[0];
}

// ---------------- K3: final reduction ----------------
__global__ __launch_bounds__(1024) void ncc_final_kernel(
    const float* __restrict__ partials, float* __restrict__ out) {
  const int t = threadIdx.x;
  float a = 0.f;
  for (int i = t; i < NPART; i += 1024) a += partials[i];
#pragma unroll
  for (int off = 32; off > 0; off >>= 1) a += __shfl_down(a, off, 64);
  __shared__ float wr[16];
  if ((t & 63) == 0) wr[t >> 6] = a;
  __syncthreads();
  if (t == 0) {
    float s = 0.f;
#pragma unroll
    for (int k = 0; k < 16; ++k) s += wr[k];
    out[0] = -s * (1.0f / (float)NTOT);
  }
}

extern "C" void kernel_launch(void* const* d_in, const int* in_sizes, int n_in,
                              void* d_out, int out_size, void* d_ws, size_t ws_size,
                              hipStream_t stream) {
  const float* fixed = (const float*)d_in[0];
  const float* warped = (const float*)d_in[1];
  float* out = (float*)d_out;

  unsigned* q = (unsigned*)d_ws;                                 // 3*NTOT uints = 98.3 MB
  float* partials = (float*)((char*)d_ws + (size_t)NTOT * 12);   // 7.7 KB

  dim3 g1(200, NHSEG);            // 1600 blocks x 256
  ncc_h_kernel<<<g1, dim3(256), 0, stream>>>(fixed, warped, q);

  dim3 g2(240, NDSEG);            // 960 waves x 8 d-segs = 1920 blocks
  ncc_dw_kernel<<<g2, dim3(256), 0, stream>>>(q, partials);

  ncc_final_kernel<<<1, dim3(1024), 0, stream>>>(partials, out);
}

// Round 13
// 57.368 us; speedup vs baseline: 1.7688x; 1.1559x over previous
//
#include <hip/hip_runtime.h>
#include <hip/hip_fp16.h>

// NCC loss: two streaming passes + tiny reduce.
// K1 (ncc_hw): wave = (b,d,chunk); lanes = staggered w (56 outputs/wave).
//   Marches H (8 segs x 20 + 8 halo) with a 5ch x 9 f32 ring + running
//   window sums, then packs to 3 half2 and does the W 9-tap IN-WAVE on
//   packed fp16 (TAP9H: 12 shuffles + 12 pk_add), storing one INTERLEAVED
//   12B record {q01,q23,q4} of HW-window sums per voxel (dwordx3 store).
// K2 (ncc_d): golden consumer: thread per (b,h,w) marches D (8 segs x 20
//   + 8) with a PACKED 9-slot ring (27 uints) fed by one dwordx3 load per
//   step; D-window = fp16 tree-sum of the 9 slots; fp32 ncc; block reduce.
//   ZERO DS ops in the loop (round-12 showed DS+VALU+mem co-dominate; W
//   moved to K1 where stores hide it).
// K3: deterministic final reduction.

constexpr int BB = 2, DD = 160, HH = 160, WW = 160;
constexpr int SLICE = HH * WW;                         // 25600
constexpr long long NTOT = (long long)BB * DD * SLICE; // 8,192,000
constexpr int HSEG = 20, NHSEG = 8;                    // K1 h-segments
constexpr int DSEG = 20, NDSEG = 8;                    // K2 d-segments
constexpr int NPART = 200 * NDSEG;                     // 1600 partials

static __device__ __forceinline__ unsigned pkh(float a, float b) {
  __half2 h = __floats2half2_rn(a, b);
  return __builtin_bit_cast(unsigned, h);
}
static __device__ __forceinline__ __half2 h2(unsigned u) {
  return __builtin_bit_cast(__half2, u);
}

// 9-tap in-wave box sum on packed __half2 (both halves independently):
// v[l] <- sum_{k=0..8} v[l+k]   (valid for lane <= 55)
#define TAP9H(v)                                                         \
  {                                                                      \
    unsigned _u = __builtin_bit_cast(unsigned, v);                       \
    __half2 _t1 = __builtin_bit_cast(__half2, __shfl_down(_u, 1, 64));   \
    __half2 _t2 = __builtin_bit_cast(__half2, __shfl_down(_u, 2, 64));   \
    v = v + _t1 + _t2;                                                   \
    _u = __builtin_bit_cast(unsigned, v);                                \
    __half2 _t3 = __builtin_bit_cast(__half2, __shfl_down(_u, 3, 64));   \
    __half2 _t6 = __builtin_bit_cast(__half2, __shfl_down(_u, 6, 64));   \
    v = v + _t3 + _t6;                                                   \
  }

// ---------------- K1: H-ring + in-wave W-tap, interleaved 12B records ----------------
__global__ __launch_bounds__(256, 4) void ncc_hw_kernel(
    const float* __restrict__ f, const float* __restrict__ w,
    unsigned* __restrict__ q) {
  const int tid = threadIdx.x;
  const int lane = tid & 63;
  const int wid = (blockIdx.x << 2) | (tid >> 6);  // 0..959 : (b,d,chunk)
  const int b = wid / 480;
  const int rem = wid % 480;
  const int d = rem / 3;
  const int ck = rem % 3;
  const int w_in = ck * 56 - 4 + lane;             // staggered input lane
  const int w_out = ck * 56 + lane;
  const bool vin = (unsigned)w_in < 160u;
  const bool vout = (lane < 56) && (w_out < 160);
  const int h0 = blockIdx.y * HSEG;
  const long long sb = (long long)(b * DD + d) * SLICE;
  const float* fr = f + sb + w_in;
  const float* wr = w + sb + w_in;

  float r0[9], r1[9], r2[9], r3[9], r4[9];
#pragma unroll
  for (int k = 0; k < 9; ++k) { r0[k] = r1[k] = r2[k] = r3[k] = r4[k] = 0.f; }
  float S0 = 0.f, S1 = 0.f, S2 = 0.f, S3 = 0.f, S4 = 0.f;

#pragma unroll
  for (int p = 0; p < HSEG + 8; ++p) {             // 28 steps
    const int j = h0 - 4 + p;                      // block-uniform guard
    float vf = 0.f, vw = 0.f;
    if ((unsigned)j < 160u && vin) {
      vf = fr[(long long)j * WW];
      vw = wr[(long long)j * WW];
    }
    const float a2 = vf * vf, a3 = vw * vw, a4 = vf * vw;
    const int sl = p % 9;                          // static after unroll
    S0 += vf - r0[sl]; r0[sl] = vf;
    S1 += vw - r1[sl]; r1[sl] = vw;
    S2 += a2 - r2[sl]; r2[sl] = a2;
    S3 += a3 - r3[sl]; r3[sl] = a3;
    S4 += a4 - r4[sl]; r4[sl] = a4;

    if (p >= 8) {
      __half2 z01 = h2(pkh(S0, S1));
      __half2 z23 = h2(pkh(S2, S3));
      __half2 z4x = h2(pkh(S4, 0.f));
      TAP9H(z01); TAP9H(z23); TAP9H(z4x);
      if (vout) {
        const long long rec = sb + (long long)(h0 + p - 8) * WW + w_out;
        unsigned* o = q + rec * 3;
        o[0] = __builtin_bit_cast(unsigned, z01);
        o[1] = __builtin_bit_cast(unsigned, z23);
        o[2] = __builtin_bit_cast(unsigned, z4x);
      }
    }
  }
}

// ---------------- K2: golden D-march consumer: packed ring + tree + ncc ----------------
__global__ __launch_bounds__(256, 4) void ncc_d_kernel(
    const unsigned* __restrict__ q, float* __restrict__ partials) {
  const int tid = threadIdx.x;
  const int g = blockIdx.x * 256 + tid;            // 0..51199 : (b, h*W+w)
  const int b = g / SLICE;                         // blocks don't straddle b
  const int r = g % SLICE;
  const int d0 = blockIdx.y * DSEG;
  const long long base = (long long)b * DD * SLICE + r;

  // packed 9-slice ring: 27 uint regs, static slots after full unroll
  unsigned g0[9], g1[9], g2[9];
#pragma unroll
  for (int k = 0; k < 9; ++k) { g0[k] = 0u; g1[k] = 0u; g2[k] = 0u; }
  float acc = 0.f;
  const float inv = 1.0f / 729.0f;

#pragma unroll
  for (int p = 0; p < DSEG + 8; ++p) {             // 28 steps
    const int j = d0 - 4 + p;                      // block-uniform guard
    unsigned u0 = 0u, u1 = 0u, u2 = 0u;
    if ((unsigned)j < 160u) {
      const long long i3 = (base + (long long)j * SLICE) * 3;
      u0 = q[i3 + 0];                              // merges to dwordx3
      u1 = q[i3 + 1];
      u2 = q[i3 + 2];
    }
    const int sl = p % 9;                          // static after unroll
    g0[sl] = u0; g1[sl] = u1; g2[sl] = u2;

    if (p >= 8) {
      // D-window = sum of ALL 9 ring slots (order-free), packed fp16 tree
      __half2 z01 = ((h2(g0[0]) + h2(g0[1])) + (h2(g0[2]) + h2(g0[3]))) +
                    ((h2(g0[4]) + h2(g0[5])) + (h2(g0[6]) + h2(g0[7]))) +
                    h2(g0[8]);
      __half2 z23 = ((h2(g1[0]) + h2(g1[1])) + (h2(g1[2]) + h2(g1[3]))) +
                    ((h2(g1[4]) + h2(g1[5])) + (h2(g1[6]) + h2(g1[7]))) +
                    h2(g1[8]);
      __half2 z4x = ((h2(g2[0]) + h2(g2[1])) + (h2(g2[2]) + h2(g2[3]))) +
                    ((h2(g2[4]) + h2(g2[5])) + (h2(g2[6]) + h2(g2[7]))) +
                    h2(g2[8]);
      const float2 a01 = __half22float2(z01);
      const float2 a23 = __half22float2(z23);
      const float2 a4v = __half22float2(z4x);
      const float fm = a01.x * inv, wm = a01.y * inv;
      const float fv = a23.x * inv - fm * fm;
      const float wv = a23.y * inv - wm * wm;
      const float cov = a4v.x * inv - fm * wm;
      const float den2 = (fmaxf(fv, 0.f) + 1e-8f) * (fmaxf(wv, 0.f) + 1e-8f);
      const float ncc = cov * rsqrtf(den2);
      acc += fminf(1.f, fmaxf(-1.f, ncc));
    }
  }

  __shared__ float red[256];
  red[tid] = acc;
  __syncthreads();
#pragma unroll
  for (int st = 128; st > 0; st >>= 1) {
    if (tid < st) red[tid] += red[tid + st];
    __syncthreads();
  }
  if (tid == 0) partials[blockIdx.y * gridDim.x + blockIdx.x] = red[0];
}

// ---------------- K3: final reduction ----------------
__global__ __launch_bounds__(1024) void ncc_final_kernel(
    const float* __restrict__ partials, float* __restrict__ out) {
  const int t = threadIdx.x;
  float a = 0.f;
  for (int i = t; i < NPART; i += 1024) a += partials[i];
#pragma unroll
  for (int off = 32; off > 0; off >>= 1) a += __shfl_down(a, off, 64);
  __shared__ float wr[16];
  if ((t & 63) == 0) wr[t >> 6] = a;
  __syncthreads();
  if (t == 0) {
    float s = 0.f;
#pragma unroll
    for (int k = 0; k < 16; ++k) s += wr[k];
    out[0] = -s * (1.0f / (float)NTOT);
  }
}

extern "C" void kernel_launch(void* const* d_in, const int* in_sizes, int n_in,
                              void* d_out, int out_size, void* d_ws, size_t ws_size,
                              hipStream_t stream) {
  const float* fixed = (const float*)d_in[0];
  const float* warped = (const float*)d_in[1];
  float* out = (float*)d_out;

  unsigned* q = (unsigned*)d_ws;                                 // 3*NTOT uints = 98.3 MB
  float* partials = (float*)((char*)d_ws + (size_t)NTOT * 12);   // 6.4 KB

  dim3 g1(240, NHSEG);            // 960 waves x 8 h-segs = 1920 blocks
  ncc_hw_kernel<<<g1, dim3(256), 0, stream>>>(fixed, warped, q);

  dim3 g2(200, NDSEG);            // 1600 blocks x 256
  ncc_d_kernel<<<g2, dim3(256), 0, stream>>>(q, partials);

  ncc_final_kernel<<<1, dim3(1024), 0, stream>>>(partials, out);
}

// Round 14
// 52.632 us; speedup vs baseline: 1.9280x; 1.0900x over previous
//
#include <hip/hip_runtime.h>
#include <hip/hip_fp16.h>

// NCC loss: two streaming passes + tiny reduce.
// K1 (ncc_hw): wave = (b,d,chunk); lanes = staggered w (56 outputs/wave).
//   Marches H (8 segs x 20 + 8 halo) with a 5ch x 9 f32 ring + running
//   window sums, packs to half2 and does the W 9-tap IN-WAVE on packed
//   fp16 (TAP9H), storing 10B/voxel: uint2 plane {(S0,S1),(S2,S3)} +
//   ushort plane {S4}  (was 12B; 10B is the 5-channel fp16 info floor).
// K2 (ncc_d): golden consumer: thread per (b,h,w) marches D (8 segs x 20
//   + 8) with a packed 9-slot ring (uint2 x9 + ushort x9) fed by one
//   dwordx2 + one ushort load per step; D-window = fp16 tree-sum of the
//   9 slots (zero-extended high halves stay exact); fp32 ncc; reduce.
// K3: deterministic final reduction.

constexpr int BB = 2, DD = 160, HH = 160, WW = 160;
constexpr int SLICE = HH * WW;                         // 25600
constexpr long long NTOT = (long long)BB * DD * SLICE; // 8,192,000
constexpr int HSEG = 20, NHSEG = 8;                    // K1 h-segments
constexpr int DSEG = 20, NDSEG = 8;                    // K2 d-segments
constexpr int NPART = 200 * NDSEG;                     // 1600 partials

static __device__ __forceinline__ unsigned pkh(float a, float b) {
  __half2 h = __floats2half2_rn(a, b);
  return __builtin_bit_cast(unsigned, h);
}
static __device__ __forceinline__ __half2 h2(unsigned u) {
  return __builtin_bit_cast(__half2, u);
}

// 9-tap in-wave box sum on packed __half2 (both halves independently):
// v[l] <- sum_{k=0..8} v[l+k]   (valid for lane <= 55)
#define TAP9H(v)                                                         \
  {                                                                      \
    unsigned _u = __builtin_bit_cast(unsigned, v);                       \
    __half2 _t1 = __builtin_bit_cast(__half2, __shfl_down(_u, 1, 64));   \
    __half2 _t2 = __builtin_bit_cast(__half2, __shfl_down(_u, 2, 64));   \
    v = v + _t1 + _t2;                                                   \
    _u = __builtin_bit_cast(unsigned, v);                                \
    __half2 _t3 = __builtin_bit_cast(__half2, __shfl_down(_u, 3, 64));   \
    __half2 _t6 = __builtin_bit_cast(__half2, __shfl_down(_u, 6, 64));   \
    v = v + _t3 + _t6;                                                   \
  }

// ---------------- K1: H-ring + in-wave W-tap, 10B/voxel output ----------------
__global__ __launch_bounds__(256, 4) void ncc_hw_kernel(
    const float* __restrict__ f, const float* __restrict__ w,
    uint2* __restrict__ qA, ushort* __restrict__ qB) {
  const int tid = threadIdx.x;
  const int lane = tid & 63;
  const int wid = (blockIdx.x << 2) | (tid >> 6);  // 0..959 : (b,d,chunk)
  const int b = wid / 480;
  const int rem = wid % 480;
  const int d = rem / 3;
  const int ck = rem % 3;
  const int w_in = ck * 56 - 4 + lane;             // staggered input lane
  const int w_out = ck * 56 + lane;
  const bool vin = (unsigned)w_in < 160u;
  const bool vout = (lane < 56) && (w_out < 160);
  const int h0 = blockIdx.y * HSEG;
  const long long sb = (long long)(b * DD + d) * SLICE;
  const float* fr = f + sb + w_in;
  const float* wr = w + sb + w_in;

  float r0[9], r1[9], r2[9], r3[9], r4[9];
#pragma unroll
  for (int k = 0; k < 9; ++k) { r0[k] = r1[k] = r2[k] = r3[k] = r4[k] = 0.f; }
  float S0 = 0.f, S1 = 0.f, S2 = 0.f, S3 = 0.f, S4 = 0.f;

#pragma unroll
  for (int p = 0; p < HSEG + 8; ++p) {             // 28 steps
    const int j = h0 - 4 + p;                      // block-uniform guard
    float vf = 0.f, vw = 0.f;
    if ((unsigned)j < 160u && vin) {
      vf = fr[(long long)j * WW];
      vw = wr[(long long)j * WW];
    }
    const float a2 = vf * vf, a3 = vw * vw, a4 = vf * vw;
    const int sl = p % 9;                          // static after unroll
    S0 += vf - r0[sl]; r0[sl] = vf;
    S1 += vw - r1[sl]; r1[sl] = vw;
    S2 += a2 - r2[sl]; r2[sl] = a2;
    S3 += a3 - r3[sl]; r3[sl] = a3;
    S4 += a4 - r4[sl]; r4[sl] = a4;

    if (p >= 8) {
      __half2 z01 = h2(pkh(S0, S1));
      __half2 z23 = h2(pkh(S2, S3));
      __half2 z4x = h2(pkh(S4, 0.f));
      TAP9H(z01); TAP9H(z23); TAP9H(z4x);
      if (vout) {
        const long long rec = sb + (long long)(h0 + p - 8) * WW + w_out;
        qA[rec] = make_uint2(__builtin_bit_cast(unsigned, z01),
                             __builtin_bit_cast(unsigned, z23));
        qB[rec] = (ushort)(__builtin_bit_cast(unsigned, z4x) & 0xFFFFu);
      }
    }
  }
}

// ---------------- K2: golden D-march consumer: packed ring + tree + ncc ----------------
__global__ __launch_bounds__(256, 4) void ncc_d_kernel(
    const uint2* __restrict__ qA, const ushort* __restrict__ qB,
    float* __restrict__ partials) {
  const int tid = threadIdx.x;
  const int g = blockIdx.x * 256 + tid;            // 0..51199 : (b, h*W+w)
  const int b = g / SLICE;                         // blocks don't straddle b
  const int r = g % SLICE;
  const int d0 = blockIdx.y * DSEG;
  const long long base = (long long)b * DD * SLICE + r;

  // packed 9-slice ring: 27 regs, static slots after full unroll
  unsigned g0[9], g1[9], g2[9];
#pragma unroll
  for (int k = 0; k < 9; ++k) { g0[k] = 0u; g1[k] = 0u; g2[k] = 0u; }
  float acc = 0.f;
  const float inv = 1.0f / 729.0f;

#pragma unroll
  for (int p = 0; p < DSEG + 8; ++p) {             // 28 steps
    const int j = d0 - 4 + p;                      // block-uniform guard
    unsigned u0 = 0u, u1 = 0u, u2v = 0u;
    if ((unsigned)j < 160u) {
      const long long i = base + (long long)j * SLICE;
      const uint2 uu = qA[i];                      // dwordx2
      u0 = uu.x; u1 = uu.y;
      u2v = (unsigned)qB[i];                       // zero-extended: high half = +0.0
    }
    const int sl = p % 9;                          // static after unroll
    g0[sl] = u0; g1[sl] = u1; g2[sl] = u2v;

    if (p >= 8) {
      // D-window = sum of ALL 9 ring slots (order-free), packed fp16 tree
      __half2 z01 = ((h2(g0[0]) + h2(g0[1])) + (h2(g0[2]) + h2(g0[3]))) +
                    ((h2(g0[4]) + h2(g0[5])) + (h2(g0[6]) + h2(g0[7]))) +
                    h2(g0[8]);
      __half2 z23 = ((h2(g1[0]) + h2(g1[1])) + (h2(g1[2]) + h2(g1[3]))) +
                    ((h2(g1[4]) + h2(g1[5])) + (h2(g1[6]) + h2(g1[7]))) +
                    h2(g1[8]);
      __half2 z4x = ((h2(g2[0]) + h2(g2[1])) + (h2(g2[2]) + h2(g2[3]))) +
                    ((h2(g2[4]) + h2(g2[5])) + (h2(g2[6]) + h2(g2[7]))) +
                    h2(g2[8]);
      const float2 a01 = __half22float2(z01);
      const float2 a23 = __half22float2(z23);
      const float a4v = __half2float(__low2half(z4x));
      const float fm = a01.x * inv, wm = a01.y * inv;
      const float fv = a23.x * inv - fm * fm;
      const float wv = a23.y * inv - wm * wm;
      const float cov = a4v * inv - fm * wm;
      const float den2 = (fmaxf(fv, 0.f) + 1e-8f) * (fmaxf(wv, 0.f) + 1e-8f);
      const float ncc = cov * rsqrtf(den2);
      acc += fminf(1.f, fmaxf(-1.f, ncc));
    }
  }

  __shared__ float red[256];
  red[tid] = acc;
  __syncthreads();
#pragma unroll
  for (int st = 128; st > 0; st >>= 1) {
    if (tid < st) red[tid] += red[tid + st];
    __syncthreads();
  }
  if (tid == 0) partials[blockIdx.y * gridDim.x + blockIdx.x] = red[0];
}

// ---------------- K3: final reduction ----------------
__global__ __launch_bounds__(1024) void ncc_final_kernel(
    const float* __restrict__ partials, float* __restrict__ out) {
  const int t = threadIdx.x;
  float a = 0.f;
  for (int i = t; i < NPART; i += 1024) a += partials[i];
#pragma unroll
  for (int off = 32; off > 0; off >>= 1) a += __shfl_down(a, off, 64);
  __shared__ float wr[16];
  if ((t & 63) == 0) wr[t >> 6] = a;
  __syncthreads();
  if (t == 0) {
    float s = 0.f;
#pragma unroll
    for (int k = 0; k < 16; ++k) s += wr[k];
    out[0] = -s * (1.0f / (float)NTOT);
  }
}

extern "C" void kernel_launch(void* const* d_in, const int* in_sizes, int n_in,
                              void* d_out, int out_size, void* d_ws, size_t ws_size,
                              hipStream_t stream) {
  const float* fixed = (const float*)d_in[0];
  const float* warped = (const float*)d_in[1];
  float* out = (float*)d_out;

  uint2* qA = (uint2*)d_ws;                                      // 65.54 MB
  ushort* qB = (ushort*)((char*)d_ws + (size_t)NTOT * 8);        // 16.38 MB
  float* partials = (float*)((char*)d_ws + (size_t)NTOT * 10);   // 6.4 KB

  dim3 g1(240, NHSEG);            // 960 waves x 8 h-segs = 1920 blocks
  ncc_hw_kernel<<<g1, dim3(256), 0, stream>>>(fixed, warped, qA, qB);

  dim3 g2(200, NDSEG);            // 1600 blocks x 256
  ncc_d_kernel<<<g2, dim3(256), 0, stream>>>(qA, qB, partials);

  ncc_final_kernel<<<1, dim3(1024), 0, stream>>>(partials, out);
}